// Round 4
// baseline (214.506 us; speedup 1.0000x reference)
//
#include <hip/hip_runtime.h>
#include <hip/hip_bf16.h>
#include <stdint.h>

#define NT 5
#define NC 32
#define NH 4
#define HW 4096             // 64*64
#define NBT 10              // b*t
#define PLANE 40960         // NBT*HW, one partial-component plane
#define QS 0.51006972789f   // (1/sqrt(8)) * log2(e): fold scale + ln->log2 into q

static __device__ __forceinline__ float bf_lo(uint32_t w) { return __uint_as_float(w << 16); }
static __device__ __forceinline__ float bf_hi(uint32_t w) { return __uint_as_float(w & 0xffff0000u); }
static __device__ __forceinline__ uint32_t pack_bf2(float a, float b) {
  union { __hip_bfloat162 h; uint32_t u; } u;
  u.h.x = __float2bfloat16(a);
  u.h.y = __float2bfloat16(b);
  return u.u;
}

// ---------------- Kernel A: QKV projection --------------------------------
// blockIdx.y in [0,8): h = by>>1, output-quad jg = by&1 (outputs h*8+jg*4 .. +3)
// q -> fp32 [bt][h][pix][8] prescaled by QS (two float4, jg picks which)
// k,v -> bf16-packed, uint2 per (pix,h,jg); adjacent jg forms the uint4 attn reads
__global__ __launch_bounds__(256) void qkv_kernel(
    const float* __restrict__ x,
    const float* __restrict__ Wq, const float* __restrict__ Wk,
    const float* __restrict__ Wv,
    float4* __restrict__ qbuf, uint2* __restrict__ kbuf, uint2* __restrict__ vbuf)
{
  const int p   = blockIdx.x * 256 + threadIdx.x;   // 0..40959
  const int by  = blockIdx.y;
  const int h   = by >> 1;
  const int jg  = by & 1;
  const int bt  = p >> 12;
  const int pix = p & 4095;

  const float* xp = x + (size_t)bt * (NC * HW) + pix;
  float xc[NC];
  #pragma unroll
  for (int c = 0; c < NC; ++c) xc[c] = xp[(size_t)c * HW];

  float qv[4], kv4[4], vv4[4];
  #pragma unroll
  for (int j = 0; j < 4; ++j) {
    const int o = h * 8 + jg * 4 + j;
    float aq = 0.f, ak = 0.f, av = 0.f;
    #pragma unroll
    for (int c = 0; c < NC; ++c) {
      const float xv = xc[c];
      aq = fmaf(xv, Wq[o * NC + c], aq);
      ak = fmaf(xv, Wk[o * NC + c], ak);
      av = fmaf(xv, Wv[o * NC + c], av);
    }
    qv[j] = aq * QS; kv4[j] = ak; vv4[j] = av;
  }
  const size_t base = (((size_t)bt * NH + h) * HW + pix) * 2 + jg;
  qbuf[base] = make_float4(qv[0], qv[1], qv[2], qv[3]);
  uint2 kk, vv;
  kk.x = pack_bf2(kv4[0], kv4[1]); kk.y = pack_bf2(kv4[2], kv4[3]);
  vv.x = pack_bf2(vv4[0], vv4[1]); vv.y = pack_bf2(vv4[2], vv4[3]);
  kbuf[base] = kk;
  vbuf[base] = vv;
}

// ---------------- Kernel B: neighborhood attention ------------------------
// ONE wave per block. Block = (query 16x8 tile) x (frame s) x (head h) x (bt).
// Writes frame-partials (l, acc[8]) per query to pbuf[s][h][comp][bt][pix].
// No running max: scores are O(+-15) in log2 units -> exp2 safe in fp32.
template <int R, int D>
static __device__ __forceinline__ void attn_body(
    int b, int t, int h, int s, int tx0, int ty0,
    const float4* __restrict__ qbuf, const uint4* __restrict__ kbuf,
    const uint4* __restrict__ vbuf, float* __restrict__ pbuf)
{
  constexpr int LS = 2 * R + 1;
  const int lane = threadIdx.x;      // 64 lanes = 64 query PAIRS (16x8 tile)
  const int py = lane >> 3;
  const int pp = lane & 7;
  const int y  = ty0 + py;
  // pair (x0, x0+D); for D==2 interleave so the 16-wide tile is covered
  const int x0 = (D == 1) ? (tx0 + 2 * pp) : (tx0 + (pp & 1) + 4 * (pp >> 1));
  const int xB = x0 + D;

  const float4* qp = qbuf + (size_t)((b * NT + t) * NH + h) * (HW * 2);
  const float4 qA0 = qp[(y * 64 + x0) * 2], qA1 = qp[(y * 64 + x0) * 2 + 1];
  const float4 qB0 = qp[(y * 64 + xB) * 2], qB1 = qp[(y * 64 + xB) * 2 + 1];

  float lA = 0.f, lB = 0.f;
  float aA[8], aB[8];
  #pragma unroll
  for (int i = 0; i < 8; ++i) { aA[i] = 0.f; aB[i] = 0.f; }

  const uint4* ks = kbuf + (size_t)((b * NT + s) * NH + h) * HW;
  const uint4* vs = vbuf + (size_t)((b * NT + s) * NH + h) * HW;

  #pragma unroll 1
  for (int dy = 0; dy < LS; ++dy) {
    const int  ky  = y + (dy - R) * D;
    const bool okY = (unsigned)ky < 64u;
    const uint4* krow = ks + (okY ? ky : 0) * 64;
    const uint4* vrow = vs + (okY ? ky : 0) * 64;
    #pragma unroll
    for (int j = 0; j <= LS; ++j) {               // key-x sweep shared by pair
      const int  kx  = x0 + (j - R) * D;
      const bool ok  = okY && ((unsigned)kx < 64u);
      const int  kxc = ok ? kx : 0;               // branchless: clamped load
      const uint4 kr = krow[kxc];
      const uint4 vr = vrow[kxc];
      const float k0 = bf_lo(kr.x), k1 = bf_hi(kr.x), k2 = bf_lo(kr.y), k3 = bf_hi(kr.y),
                  k4 = bf_lo(kr.z), k5 = bf_hi(kr.z), k6 = bf_lo(kr.w), k7 = bf_hi(kr.w);
      const float v0 = bf_lo(vr.x), v1 = bf_hi(vr.x), v2 = bf_lo(vr.y), v3 = bf_hi(vr.y),
                  v4 = bf_lo(vr.z), v5 = bf_hi(vr.z), v6 = bf_lo(vr.w), v7 = bf_hi(vr.w);
      if (j < LS) {                               // query A uses j = 0..LS-1
        const float e = fmaf(qA1.w, k7, fmaf(qA1.z, k6, fmaf(qA1.y, k5, fmaf(qA1.x, k4,
                        fmaf(qA0.w, k3, fmaf(qA0.z, k2, fmaf(qA0.y, k1, qA0.x * k0)))))));
        const float p = ok ? exp2f(e) : 0.f;
        lA += p;
        aA[0] = fmaf(p, v0, aA[0]); aA[1] = fmaf(p, v1, aA[1]);
        aA[2] = fmaf(p, v2, aA[2]); aA[3] = fmaf(p, v3, aA[3]);
        aA[4] = fmaf(p, v4, aA[4]); aA[5] = fmaf(p, v5, aA[5]);
        aA[6] = fmaf(p, v6, aA[6]); aA[7] = fmaf(p, v7, aA[7]);
      }
      if (j > 0) {                                // query B uses j = 1..LS
        const float e = fmaf(qB1.w, k7, fmaf(qB1.z, k6, fmaf(qB1.y, k5, fmaf(qB1.x, k4,
                        fmaf(qB0.w, k3, fmaf(qB0.z, k2, fmaf(qB0.y, k1, qB0.x * k0)))))));
        const float p = ok ? exp2f(e) : 0.f;
        lB += p;
        aB[0] = fmaf(p, v0, aB[0]); aB[1] = fmaf(p, v1, aB[1]);
        aB[2] = fmaf(p, v2, aB[2]); aB[3] = fmaf(p, v3, aB[3]);
        aB[4] = fmaf(p, v4, aB[4]); aB[5] = fmaf(p, v5, aB[5]);
        aB[6] = fmaf(p, v6, aB[6]); aB[7] = fmaf(p, v7, aB[7]);
      }
    }
  }

  // ---- store frame-partials: pbuf[s][h][comp(9)][bt][pix] ----
  const int bt   = b * NT + t;
  const int pixA = y * 64 + x0, pixB = y * 64 + xB;
  float* pb = pbuf + (size_t)((s * NH + h) * 9) * PLANE + (size_t)bt * HW;
  #pragma unroll
  for (int i = 0; i < 8; ++i) {
    pb[(size_t)i * PLANE + pixA] = aA[i];
    pb[(size_t)i * PLANE + pixB] = aB[i];
  }
  pb[(size_t)8 * PLANE + pixA] = lA;
  pb[(size_t)8 * PLANE + pixB] = lB;
}

__global__ __launch_bounds__(64) void attn_kernel(
    const float4* __restrict__ qbuf, const uint4* __restrict__ kbuf,
    const uint4* __restrict__ vbuf, float* __restrict__ pbuf)
{
  const int bid = blockIdx.x;        // 6400 = 10(bt) * 32(tile) * 5(s) * 4(h)
  const int h   = bid & 3;           // head in low bits -> R3/R4 mix per CU
  const int s   = (bid >> 2) % 5;
  const int r   = (bid >> 2) / 5;    // 0..319
  const int tile = r & 31;
  const int bt   = r >> 5;
  const int t = bt % NT, b = bt / NT;
  const int tx0 = (tile & 3) * 16;
  const int ty0 = (tile >> 2) * 8;
  if      (h == 0) attn_body<3, 1>(b, t, 0, s, tx0, ty0, qbuf, kbuf, vbuf, pbuf);
  else if (h == 1) attn_body<3, 2>(b, t, 1, s, tx0, ty0, qbuf, kbuf, vbuf, pbuf);
  else if (h == 2) attn_body<4, 1>(b, t, 2, s, tx0, ty0, qbuf, kbuf, vbuf, pbuf);
  else             attn_body<4, 2>(b, t, 3, s, tx0, ty0, qbuf, kbuf, vbuf, pbuf);
}

// ---------------- Kernel C: reduce partials + output projection + residual ----
// blockIdx.y = out-channel group (8 channels). All loads fully coalesced.
__global__ __launch_bounds__(256) void proj_kernel(
    const float* __restrict__ pbuf, const float* __restrict__ x,
    const float* __restrict__ Wo, float* __restrict__ out)
{
  const int p   = blockIdx.x * 256 + threadIdx.x;   // 0..40959
  const int og  = blockIdx.y;
  const int bt  = p >> 12;
  const int pix = p & 4095;

  float oc[32];
  #pragma unroll
  for (int h = 0; h < NH; ++h) {
    float a[8], l = 0.f;
    #pragma unroll
    for (int i = 0; i < 8; ++i) a[i] = 0.f;
    #pragma unroll
    for (int s = 0; s < NT; ++s) {
      const float* pb = pbuf + (size_t)((s * NH + h) * 9) * PLANE + (size_t)bt * HW + pix;
      #pragma unroll
      for (int i = 0; i < 8; ++i) a[i] += pb[(size_t)i * PLANE];
      l += pb[(size_t)8 * PLANE];
    }
    const float inv = 1.0f / l;
    #pragma unroll
    for (int i = 0; i < 8; ++i) oc[h * 8 + i] = a[i] * inv;
  }

  const float* xp = x + (size_t)bt * (NC * HW) + pix;
  float* yp = out + (size_t)bt * (NC * HW) + pix;
  #pragma unroll
  for (int oo = 0; oo < 8; ++oo) {
    const int o = og * 8 + oo;
    float acc = xp[(size_t)o * HW];              // residual
    #pragma unroll
    for (int c = 0; c < NC; ++c)
      acc = fmaf(oc[c], Wo[o * NC + c], acc);
    yp[(size_t)o * HW] = acc;
  }
}

extern "C" void kernel_launch(void* const* d_in, const int* in_sizes, int n_in,
                              void* d_out, int out_size, void* d_ws, size_t ws_size,
                              hipStream_t stream)
{
  const float* x  = (const float*)d_in[0];
  const float* Wq = (const float*)d_in[1];
  const float* Wk = (const float*)d_in[2];
  const float* Wv = (const float*)d_in[3];
  const float* Wo = (const float*)d_in[4];

  char* ws = (char*)d_ws;
  float4* qbuf = (float4*)ws;                           //  5,242,880 B
  uint2*  kbuf = (uint2*)(ws + 5242880);                //  2,621,440 B
  uint2*  vbuf = (uint2*)(ws + 5242880 + 2621440);      //  2,621,440 B
  float*  pbuf = (float*)(ws + 5242880 + 2 * 2621440);  // 29,491,200 B

  qkv_kernel<<<dim3(160, 8), 256, 0, stream>>>(x, Wq, Wk, Wv, qbuf, kbuf, vbuf);
  attn_kernel<<<6400, 64, 0, stream>>>(qbuf, (const uint4*)kbuf, (const uint4*)vbuf, pbuf);
  proj_kernel<<<dim3(160, 4), 256, 0, stream>>>(pbuf, x, Wo, (float*)d_out);
}

// Round 5
// 158.398 us; speedup vs baseline: 1.3542x; 1.3542x over previous
//
#include <hip/hip_runtime.h>
#include <hip/hip_bf16.h>
#include <stdint.h>

#define NT 5
#define NC 32
#define NH 4
#define HW 4096             // 64*64
#define NBT 10              // b*t
#define PLANE 40960         // NBT*HW, one partial-component plane
#define QS 0.51006972789f   // (1/sqrt(8)) * log2(e): fold scale + ln->log2 into q

static __device__ __forceinline__ float bf_lo(uint32_t w) { return __uint_as_float(w << 16); }
static __device__ __forceinline__ float bf_hi(uint32_t w) { return __uint_as_float(w & 0xffff0000u); }
static __device__ __forceinline__ uint32_t pack_bf2(float a, float b) {
  union { __hip_bfloat162 h; uint32_t u; } u;
  u.h.x = __float2bfloat16(a);
  u.h.y = __float2bfloat16(b);
  return u.u;
}

// ---------------- Kernel A: QKV projection (head per blockIdx.y) ------------
// q -> fp32 [bt][h][pix][8] prescaled by QS; k,v -> bf16-packed uint4 [bt][h][pix]
__global__ __launch_bounds__(256) void qkv_kernel(
    const float* __restrict__ x,
    const float* __restrict__ Wq, const float* __restrict__ Wk,
    const float* __restrict__ Wv,
    float4* __restrict__ qbuf, uint4* __restrict__ kbuf, uint4* __restrict__ vbuf)
{
  const int p   = blockIdx.x * 256 + threadIdx.x;   // 0..40959
  const int h   = blockIdx.y;
  const int bt  = p >> 12;
  const int pix = p & 4095;

  const float* xp = x + (size_t)bt * (NC * HW) + pix;
  float xc[NC];
  #pragma unroll
  for (int c = 0; c < NC; ++c) xc[c] = xp[(size_t)c * HW];

  float qv[8], kv8[8], vv8[8];
  #pragma unroll
  for (int j = 0; j < 8; ++j) {
    const int o = h * 8 + j;
    float aq = 0.f, ak = 0.f, av = 0.f;
    #pragma unroll
    for (int c = 0; c < NC; ++c) {
      const float xv = xc[c];
      aq = fmaf(xv, Wq[o * NC + c], aq);
      ak = fmaf(xv, Wk[o * NC + c], ak);
      av = fmaf(xv, Wv[o * NC + c], av);
    }
    qv[j] = aq * QS; kv8[j] = ak; vv8[j] = av;
  }
  const size_t base = ((size_t)bt * NH + h) * HW + pix;
  qbuf[base * 2]     = make_float4(qv[0], qv[1], qv[2], qv[3]);
  qbuf[base * 2 + 1] = make_float4(qv[4], qv[5], qv[6], qv[7]);
  uint4 kk, vv;
  kk.x = pack_bf2(kv8[0], kv8[1]); kk.y = pack_bf2(kv8[2], kv8[3]);
  kk.z = pack_bf2(kv8[4], kv8[5]); kk.w = pack_bf2(kv8[6], kv8[7]);
  vv.x = pack_bf2(vv8[0], vv8[1]); vv.y = pack_bf2(vv8[2], vv8[3]);
  vv.z = pack_bf2(vv8[4], vv8[5]); vv.w = pack_bf2(vv8[6], vv8[7]);
  kbuf[base] = kk;
  vbuf[base] = vv;
}

// ---------------- Kernel B: neighborhood attention, LDS-staged --------------
// Block = 256 thr = 4 waves; lanes = 64 x-positions of a row; each wave owns a
// vertical query pair (y, y+D) sharing the key-row sweep. One frame per block.
// D=2 rows are parity-deinterleaved in LDS so reads stay lane-contiguous.
template <int R, int D>
static __device__ __forceinline__ void attn_body(
    int b, int t, int h, int s, int yb,
    const float4* __restrict__ qbuf, const uint4* __restrict__ kbuf,
    const uint4* __restrict__ vbuf, float* __restrict__ pbuf,
    uint4* __restrict__ k_lds, uint4* __restrict__ v_lds)
{
  constexpr int LS    = 2 * R + 1;
  constexpr int NROWS = 8 + 2 * R;        // staged key rows (step D)
  const int tid  = threadIdx.x;
  const int w    = tid >> 6;              // wave 0..3
  const int lane = tid & 63;

  // first query row of this block (D2: yb&1 = row parity, 8 same-parity rows)
  const int y0 = (D == 1) ? (yb * 8) : ((yb & 1) + 2 * ((yb >> 1) * 8));

  // ---- stage NROWS full-width K,V rows into LDS (coalesced) ----
  const uint4* kg = kbuf + (size_t)((b * NT + s) * NH + h) * HW;
  const uint4* vg = vbuf + (size_t)((b * NT + s) * NH + h) * HW;
  for (int idx = tid; idx < NROWS * 64; idx += 256) {
    const int r  = idx >> 6, xs = idx & 63;
    int ys = y0 + (r - R) * D;
    ys = ys < 0 ? 0 : (ys > 63 ? 63 : ys);          // clamp; masked at compute
    const int pos = (D == 1) ? xs : ((xs & 1) * 32 + (xs >> 1));
    k_lds[r * 64 + pos] = kg[ys * 64 + xs];
    v_lds[r * 64 + pos] = vg[ys * 64 + xs];
  }
  __syncthreads();

  const int xp = lane >> 5;                          // D2 x-parity
  const int cb = (D == 1) ? lane : (lane & 31);      // compressed x
  const int x  = (D == 1) ? lane : (2 * (lane & 31) + xp);
  const int yA = y0 + 2 * w * D;
  const int yB = yA + D;
  const int pixA = yA * 64 + x, pixB = yB * 64 + x;

  const float4* qp = qbuf + (size_t)((b * NT + t) * NH + h) * (HW * 2);
  const float4 qA0 = qp[pixA * 2], qA1 = qp[pixA * 2 + 1];
  const float4 qB0 = qp[pixB * 2], qB1 = qp[pixB * 2 + 1];

  float lA = 0.f, lB = 0.f;
  float aA[8], aB[8];
  #pragma unroll
  for (int i = 0; i < 8; ++i) { aA[i] = 0.f; aB[i] = 0.f; }

  #pragma unroll 1
  for (int u = 0; u <= LS; ++u) {                    // key-row sweep, pair-shared
    const bool okA = (u < LS) && ((unsigned)(yA + (u - R) * D) < 64u);
    const bool okB = (u > 0)  && ((unsigned)(yB + (u - 1 - R) * D) < 64u);
    if (!(okA || okB)) continue;                     // wave-uniform skip
    const float mA = okA ? 1.f : 0.f, mB = okB ? 1.f : 0.f;
    const uint4* kr = k_lds + (2 * w + u) * 64;
    const uint4* vr = v_lds + (2 * w + u) * 64;
    #pragma unroll
    for (int dx = -R; dx <= R; ++dx) {
      const int  cx  = cb + dx;
      const bool okx = (unsigned)cx < (D == 1 ? 64u : 32u);
      const int  cc  = okx ? cx : 0;
      const int  pos = (D == 1) ? cc : (xp * 32 + cc);
      const uint4 kk = kr[pos];
      const uint4 vv = vr[pos];
      const float k0 = bf_lo(kk.x), k1 = bf_hi(kk.x), k2 = bf_lo(kk.y), k3 = bf_hi(kk.y),
                  k4 = bf_lo(kk.z), k5 = bf_hi(kk.z), k6 = bf_lo(kk.w), k7 = bf_hi(kk.w);
      const float v0 = bf_lo(vv.x), v1 = bf_hi(vv.x), v2 = bf_lo(vv.y), v3 = bf_hi(vv.y),
                  v4 = bf_lo(vv.z), v5 = bf_hi(vv.z), v6 = bf_lo(vv.w), v7 = bf_hi(vv.w);
      const float eA = fmaf(qA1.w, k7, fmaf(qA1.z, k6, fmaf(qA1.y, k5, fmaf(qA1.x, k4,
                      fmaf(qA0.w, k3, fmaf(qA0.z, k2, fmaf(qA0.y, k1, qA0.x * k0)))))));
      const float eB = fmaf(qB1.w, k7, fmaf(qB1.z, k6, fmaf(qB1.y, k5, fmaf(qB1.x, k4,
                      fmaf(qB0.w, k3, fmaf(qB0.z, k2, fmaf(qB0.y, k1, qB0.x * k0)))))));
      const float pA = (okx ? exp2f(eA) : 0.f) * mA;
      const float pB = (okx ? exp2f(eB) : 0.f) * mB;
      lA += pA; lB += pB;
      aA[0] = fmaf(pA, v0, aA[0]); aA[1] = fmaf(pA, v1, aA[1]);
      aA[2] = fmaf(pA, v2, aA[2]); aA[3] = fmaf(pA, v3, aA[3]);
      aA[4] = fmaf(pA, v4, aA[4]); aA[5] = fmaf(pA, v5, aA[5]);
      aA[6] = fmaf(pA, v6, aA[6]); aA[7] = fmaf(pA, v7, aA[7]);
      aB[0] = fmaf(pB, v0, aB[0]); aB[1] = fmaf(pB, v1, aB[1]);
      aB[2] = fmaf(pB, v2, aB[2]); aB[3] = fmaf(pB, v3, aB[3]);
      aB[4] = fmaf(pB, v4, aB[4]); aB[5] = fmaf(pB, v5, aB[5]);
      aB[6] = fmaf(pB, v6, aB[6]); aB[7] = fmaf(pB, v7, aB[7]);
    }
  }

  // ---- frame-partials: pbuf[s][h][comp(9)][bt][pix], lane-coalesced ----
  float* pb = pbuf + (size_t)((s * NH + h) * 9) * PLANE + (size_t)(b * NT + t) * HW;
  #pragma unroll
  for (int i = 0; i < 8; ++i) {
    pb[(size_t)i * PLANE + pixA] = aA[i];
    pb[(size_t)i * PLANE + pixB] = aB[i];
  }
  pb[(size_t)8 * PLANE + pixA] = lA;
  pb[(size_t)8 * PLANE + pixB] = lB;
}

__global__ __launch_bounds__(256) void attn_kernel(
    const float4* __restrict__ qbuf, const uint4* __restrict__ kbuf,
    const uint4* __restrict__ vbuf, float* __restrict__ pbuf)
{
  __shared__ uint4 k_lds[16 * 64];   // 16 KB
  __shared__ uint4 v_lds[16 * 64];   // 16 KB
  const int bid = blockIdx.x;        // 1600 = 10(bt) * 5(s) * 8(yb) * 4(h)
  const int h   = bid & 3;           // head in low bits -> R3/R4 mix per CU
  int r = bid >> 2;
  const int yb = r & 7; r >>= 3;
  const int s  = r % 5;
  const int bt = r / 5;
  const int t = bt % NT, b = bt / NT;
  if      (h == 0) attn_body<3, 1>(b, t, 0, s, yb, qbuf, kbuf, vbuf, pbuf, k_lds, v_lds);
  else if (h == 1) attn_body<3, 2>(b, t, 1, s, yb, qbuf, kbuf, vbuf, pbuf, k_lds, v_lds);
  else if (h == 2) attn_body<4, 1>(b, t, 2, s, yb, qbuf, kbuf, vbuf, pbuf, k_lds, v_lds);
  else             attn_body<4, 2>(b, t, 3, s, yb, qbuf, kbuf, vbuf, pbuf, k_lds, v_lds);
}

// ---------------- Kernel C: reduce frame-partials -> oc[btpix][32] ----------
__global__ __launch_bounds__(256) void reduce_kernel(
    const float* __restrict__ pbuf, float* __restrict__ oc)
{
  const int btpix = blockIdx.x * 256 + threadIdx.x;   // 0..40959
  const int h     = blockIdx.y;
  float a[8], l = 0.f;
  #pragma unroll
  for (int i = 0; i < 8; ++i) a[i] = 0.f;
  #pragma unroll
  for (int s = 0; s < NT; ++s) {
    const float* pb = pbuf + (size_t)((s * NH + h) * 9) * PLANE + btpix;
    #pragma unroll
    for (int i = 0; i < 8; ++i) a[i] += pb[(size_t)i * PLANE];
    l += pb[(size_t)8 * PLANE];
  }
  const float inv = 1.0f / l;
  float4* o4 = (float4*)(oc + (size_t)btpix * 32 + h * 8);
  o4[0] = make_float4(a[0] * inv, a[1] * inv, a[2] * inv, a[3] * inv);
  o4[1] = make_float4(a[4] * inv, a[5] * inv, a[6] * inv, a[7] * inv);
}

// ---------------- Kernel D: output projection + residual --------------------
__global__ __launch_bounds__(256) void proj_kernel(
    const float* __restrict__ oc, const float* __restrict__ x,
    const float* __restrict__ Wo, float* __restrict__ out)
{
  const int p   = blockIdx.x * 256 + threadIdx.x;   // 0..40959
  const int og  = blockIdx.y;                       // 8 out-channels per og
  const int bt  = p >> 12;
  const int pix = p & 4095;

  const float4* op4 = (const float4*)(oc + (size_t)p * 32);
  float c32[32];
  #pragma unroll
  for (int i = 0; i < 8; ++i) {
    const float4 t4 = op4[i];
    c32[4 * i] = t4.x; c32[4 * i + 1] = t4.y; c32[4 * i + 2] = t4.z; c32[4 * i + 3] = t4.w;
  }
  const float* xp = x + (size_t)bt * (NC * HW) + pix;
  float* yp = out + (size_t)bt * (NC * HW) + pix;
  #pragma unroll
  for (int oo = 0; oo < 8; ++oo) {
    const int o = og * 8 + oo;
    float acc = xp[(size_t)o * HW];                 // residual
    #pragma unroll
    for (int c = 0; c < NC; ++c)
      acc = fmaf(c32[c], Wo[o * NC + c], acc);
    yp[(size_t)o * HW] = acc;
  }
}

extern "C" void kernel_launch(void* const* d_in, const int* in_sizes, int n_in,
                              void* d_out, int out_size, void* d_ws, size_t ws_size,
                              hipStream_t stream)
{
  const float* x  = (const float*)d_in[0];
  const float* Wq = (const float*)d_in[1];
  const float* Wk = (const float*)d_in[2];
  const float* Wv = (const float*)d_in[3];
  const float* Wo = (const float*)d_in[4];

  char* ws = (char*)d_ws;
  float4* qbuf = (float4*)ws;                           //  5,242,880 B
  uint4*  kbuf = (uint4*)(ws + 5242880);                //  2,621,440 B
  uint4*  vbuf = (uint4*)(ws + 5242880 + 2621440);      //  2,621,440 B
  float*  pbuf = (float*)(ws + 5242880 + 2 * 2621440);  // 29,491,200 B
  float*  oc   = (float*)ws;  // reuses qbuf region after attn (5,242,880 B)

  qkv_kernel<<<dim3(160, 4), 256, 0, stream>>>(x, Wq, Wk, Wv, qbuf, kbuf, vbuf);
  attn_kernel<<<1600, 256, 0, stream>>>(qbuf, kbuf, vbuf, pbuf);
  reduce_kernel<<<dim3(160, 4), 256, 0, stream>>>(pbuf, oc);
  proj_kernel<<<dim3(160, 4), 256, 0, stream>>>(oc, x, Wo, (float*)d_out);
}

// Round 6
// 138.261 us; speedup vs baseline: 1.5515x; 1.1456x over previous
//
#include <hip/hip_runtime.h>
#include <stdint.h>

#define NT 5
#define NC 32
#define NH 4
#define HW 4096             // 64*64
#define NBT 10              // b*t
#define NPIX 40960          // NBT*HW
#define QS 0.51006972789f   // (1/sqrt(8)) * log2(e): fold scale + ln->log2 into q

typedef _Float16 half_t;
typedef half_t h2 __attribute__((ext_vector_type(2)));

static __device__ __forceinline__ h2 as_h2(uint32_t u) {
  union { uint32_t u; h2 h; } c; c.u = u; return c.h;
}
static __device__ __forceinline__ uint32_t pack_h2(float a, float b) {
  union { h2 h; uint32_t u; } c;
  c.h.x = (half_t)a; c.h.y = (half_t)b;
  return c.u;
}

#if __has_builtin(__builtin_amdgcn_exp2f)
#define EXP2(x) __builtin_amdgcn_exp2f(x)
#else
#define EXP2(x) exp2f(x)
#endif

static __device__ __forceinline__ float dot8(const uint4& a, const uint4& b) {
#if __has_builtin(__builtin_amdgcn_fdot2)
  float c = 0.f;
  c = __builtin_amdgcn_fdot2(as_h2(a.x), as_h2(b.x), c, false);
  c = __builtin_amdgcn_fdot2(as_h2(a.y), as_h2(b.y), c, false);
  c = __builtin_amdgcn_fdot2(as_h2(a.z), as_h2(b.z), c, false);
  c = __builtin_amdgcn_fdot2(as_h2(a.w), as_h2(b.w), c, false);
  return c;
#else
  const h2 a0 = as_h2(a.x), a1 = as_h2(a.y), a2 = as_h2(a.z), a3 = as_h2(a.w);
  const h2 b0 = as_h2(b.x), b1 = as_h2(b.y), b2 = as_h2(b.z), b3 = as_h2(b.w);
  float c = (float)a0.x * (float)b0.x;
  c = fmaf((float)a0.y, (float)b0.y, c);
  c = fmaf((float)a1.x, (float)b1.x, c);
  c = fmaf((float)a1.y, (float)b1.y, c);
  c = fmaf((float)a2.x, (float)b2.x, c);
  c = fmaf((float)a2.y, (float)b2.y, c);
  c = fmaf((float)a3.x, (float)b3.x, c);
  c = fmaf((float)a3.y, (float)b3.y, c);
  return c;
#endif
}

static __device__ __forceinline__ void unp8(const uint4& v, float (&o)[8]) {
  const h2 v0 = as_h2(v.x), v1 = as_h2(v.y), v2 = as_h2(v.z), v3 = as_h2(v.w);
  o[0] = (float)v0.x; o[1] = (float)v0.y; o[2] = (float)v1.x; o[3] = (float)v1.y;
  o[4] = (float)v2.x; o[5] = (float)v2.y; o[6] = (float)v3.x; o[7] = (float)v3.y;
}

// ---------------- Kernel A: QKV projection (head per blockIdx.y) ------------
// q,k,v -> fp16-packed uint4 [bt][h][pix]; q prescaled by QS.
// Also zeroes the 36-plane fp32 accumulator (re-zeroed every call).
__global__ __launch_bounds__(256) void qkv_kernel(
    const float* __restrict__ x,
    const float* __restrict__ Wq, const float* __restrict__ Wk,
    const float* __restrict__ Wv,
    uint4* __restrict__ qf, uint4* __restrict__ kf, uint4* __restrict__ vf,
    float* __restrict__ accbuf)
{
  const int p   = blockIdx.x * 256 + threadIdx.x;   // 0..40959
  const int h   = blockIdx.y;
  const int bt  = p >> 12;
  const int pix = p & 4095;

  // zero accumulator: 36*NPIX floats == 9 per (thread, blockIdx.y)
  const int gid = (blockIdx.y * 160 + blockIdx.x) * 256 + threadIdx.x; // 0..163839
  #pragma unroll
  for (int i = 0; i < 9; ++i) accbuf[(size_t)i * 163840 + gid] = 0.f;

  const float* xp = x + (size_t)bt * (NC * HW) + pix;
  float xc[NC];
  #pragma unroll
  for (int c = 0; c < NC; ++c) xc[c] = xp[(size_t)c * HW];

  float qv[8], kv8[8], vv8[8];
  #pragma unroll
  for (int j = 0; j < 8; ++j) {
    const int o = h * 8 + j;
    float aq = 0.f, ak = 0.f, av = 0.f;
    #pragma unroll
    for (int c = 0; c < NC; ++c) {
      const float xv = xc[c];
      aq = fmaf(xv, Wq[o * NC + c], aq);
      ak = fmaf(xv, Wk[o * NC + c], ak);
      av = fmaf(xv, Wv[o * NC + c], av);
    }
    qv[j] = aq * QS; kv8[j] = ak; vv8[j] = av;
  }
  const size_t base = ((size_t)bt * NH + h) * HW + pix;
  uint4 qq, kk, vv;
  qq.x = pack_h2(qv[0], qv[1]);  qq.y = pack_h2(qv[2], qv[3]);
  qq.z = pack_h2(qv[4], qv[5]);  qq.w = pack_h2(qv[6], qv[7]);
  kk.x = pack_h2(kv8[0], kv8[1]); kk.y = pack_h2(kv8[2], kv8[3]);
  kk.z = pack_h2(kv8[4], kv8[5]); kk.w = pack_h2(kv8[6], kv8[7]);
  vv.x = pack_h2(vv8[0], vv8[1]); vv.y = pack_h2(vv8[2], vv8[3]);
  vv.z = pack_h2(vv8[4], vv8[5]); vv.w = pack_h2(vv8[6], vv8[7]);
  qf[base] = qq;
  kf[base] = kk;
  vf[base] = vv;
}

// ---------------- Kernel B: neighborhood attention, LDS-staged --------------
// Block = 256 thr = 4 waves; lanes = 64 x-positions of a row; each wave owns a
// vertical query pair (y, y+D) sharing the key-row sweep. One frame per block.
// Frame-partials accumulated via fp32 global atomics: accbuf[h][comp9][btpix].
template <int R, int D>
static __device__ __forceinline__ void attn_body(
    int b, int t, int h, int s, int yb,
    const uint4* __restrict__ qf, const uint4* __restrict__ kf,
    const uint4* __restrict__ vf, float* __restrict__ accbuf,
    uint4* __restrict__ k_lds, uint4* __restrict__ v_lds)
{
  constexpr int LS    = 2 * R + 1;
  constexpr int NROWS = 8 + 2 * R;        // staged key rows (step D)
  const int tid  = threadIdx.x;
  const int w    = tid >> 6;              // wave 0..3
  const int lane = tid & 63;

  // first query row of this block (D2: yb&1 = row parity, 8 same-parity rows)
  const int y0 = (D == 1) ? (yb * 8) : ((yb & 1) + 2 * ((yb >> 1) * 8));

  // ---- stage NROWS full-width K,V rows into LDS (coalesced) ----
  const uint4* kg = kf + (size_t)((b * NT + s) * NH + h) * HW;
  const uint4* vg = vf + (size_t)((b * NT + s) * NH + h) * HW;
  for (int idx = tid; idx < NROWS * 64; idx += 256) {
    const int r  = idx >> 6, xs = idx & 63;
    int ys = y0 + (r - R) * D;
    ys = ys < 0 ? 0 : (ys > 63 ? 63 : ys);          // clamp; masked at compute
    const int pos = (D == 1) ? xs : ((xs & 1) * 32 + (xs >> 1));
    k_lds[r * 64 + pos] = kg[ys * 64 + xs];
    v_lds[r * 64 + pos] = vg[ys * 64 + xs];
  }
  __syncthreads();

  const int xp = lane >> 5;                          // D2 x-parity
  const int cb = (D == 1) ? lane : (lane & 31);      // compressed x
  const int x  = (D == 1) ? lane : (2 * (lane & 31) + xp);
  const int yA = y0 + 2 * w * D;
  const int yB = yA + D;
  const int pixA = yA * 64 + x, pixB = yB * 64 + x;

  const uint4* qp = qf + (size_t)((b * NT + t) * NH + h) * HW;
  const uint4 qA = qp[pixA];
  const uint4 qB = qp[pixB];

  float lA = 0.f, lB = 0.f;
  float aA[8], aB[8];
  #pragma unroll
  for (int i = 0; i < 8; ++i) { aA[i] = 0.f; aB[i] = 0.f; }

  #pragma unroll 1
  for (int u = 0; u <= LS; ++u) {                    // key-row sweep, pair-shared
    const bool okA = (u < LS) && ((unsigned)(yA + (u - R) * D) < 64u);
    const bool okB = (u > 0)  && ((unsigned)(yB + (u - 1 - R) * D) < 64u);
    if (!(okA || okB)) continue;                     // wave-uniform skip
    const float mA = okA ? 1.f : 0.f, mB = okB ? 1.f : 0.f;
    const uint4* kr = k_lds + (2 * w + u) * 64;
    const uint4* vr = v_lds + (2 * w + u) * 64;
    #pragma unroll
    for (int dx = -R; dx <= R; ++dx) {
      const int  cx  = cb + dx;
      const bool okx = (unsigned)cx < (D == 1 ? 64u : 32u);
      const int  cc  = okx ? cx : 0;
      const int  pos = (D == 1) ? cc : (xp * 32 + cc);
      const uint4 kk = kr[pos];
      const uint4 vv = vr[pos];
      float v8[8];
      unp8(vv, v8);
      const float eA = dot8(qA, kk);
      const float eB = dot8(qB, kk);
      const float pA = (okx ? mA : 0.f) * EXP2(eA);
      const float pB = (okx ? mB : 0.f) * EXP2(eB);
      lA += pA; lB += pB;
      #pragma unroll
      for (int i = 0; i < 8; ++i) {
        aA[i] = fmaf(pA, v8[i], aA[i]);
        aB[i] = fmaf(pB, v8[i], aB[i]);
      }
    }
  }

  // ---- accumulate frame-partials: accbuf[h][comp(9)][btpix] ----
  const int btA = (b * NT + t) * HW + pixA;
  const int btB = (b * NT + t) * HW + pixB;
  float* ab = accbuf + (size_t)(h * 9) * NPIX;
  #pragma unroll
  for (int i = 0; i < 8; ++i) {
    atomicAdd(&ab[(size_t)i * NPIX + btA], aA[i]);
    atomicAdd(&ab[(size_t)i * NPIX + btB], aB[i]);
  }
  atomicAdd(&ab[(size_t)8 * NPIX + btA], lA);
  atomicAdd(&ab[(size_t)8 * NPIX + btB], lB);
}

__global__ __launch_bounds__(256) void attn_kernel(
    const uint4* __restrict__ qf, const uint4* __restrict__ kf,
    const uint4* __restrict__ vf, float* __restrict__ accbuf)
{
  __shared__ uint4 k_lds[16 * 64];   // 16 KB
  __shared__ uint4 v_lds[16 * 64];   // 16 KB
  const int bid = blockIdx.x;        // 1600 = 10(bt) * 5(s) * 8(yb) * 4(h)
  const int h   = bid & 3;           // head in low bits -> R3/R4 mix per CU
  int r = bid >> 2;
  const int yb = r & 7; r >>= 3;
  const int s  = r % 5;
  const int bt = r / 5;
  const int t = bt % NT, b = bt / NT;
  if      (h == 0) attn_body<3, 1>(b, t, 0, s, yb, qf, kf, vf, accbuf, k_lds, v_lds);
  else if (h == 1) attn_body<3, 2>(b, t, 1, s, yb, qf, kf, vf, accbuf, k_lds, v_lds);
  else if (h == 2) attn_body<4, 1>(b, t, 2, s, yb, qf, kf, vf, accbuf, k_lds, v_lds);
  else             attn_body<4, 2>(b, t, 3, s, yb, qf, kf, vf, accbuf, k_lds, v_lds);
}

// ---------------- Kernel C: normalize + output projection + residual --------
__global__ __launch_bounds__(64) void proj_kernel(
    const float* __restrict__ accbuf, const float* __restrict__ x,
    const float* __restrict__ Wo, float* __restrict__ out)
{
  const int p   = blockIdx.x * 64 + threadIdx.x;   // btpix 0..40959
  const int bt  = p >> 12;
  const int pix = p & 4095;

  float oc[32];
  #pragma unroll
  for (int h = 0; h < NH; ++h) {
    const float* ab = accbuf + (size_t)(h * 9) * NPIX + p;
    float a[8];
    #pragma unroll
    for (int i = 0; i < 8; ++i) a[i] = ab[(size_t)i * NPIX];
    const float inv = 1.0f / ab[(size_t)8 * NPIX];
    #pragma unroll
    for (int i = 0; i < 8; ++i) oc[h * 8 + i] = a[i] * inv;
  }

  const float* xp = x + (size_t)bt * (NC * HW) + pix;
  float* yp = out + (size_t)bt * (NC * HW) + pix;
  #pragma unroll
  for (int o = 0; o < NC; ++o) {
    float acc = xp[(size_t)o * HW];                 // residual
    #pragma unroll
    for (int c = 0; c < NC; ++c)
      acc = fmaf(oc[c], Wo[o * NC + c], acc);
    yp[(size_t)o * HW] = acc;
  }
}

extern "C" void kernel_launch(void* const* d_in, const int* in_sizes, int n_in,
                              void* d_out, int out_size, void* d_ws, size_t ws_size,
                              hipStream_t stream)
{
  const float* x  = (const float*)d_in[0];
  const float* Wq = (const float*)d_in[1];
  const float* Wk = (const float*)d_in[2];
  const float* Wv = (const float*)d_in[3];
  const float* Wo = (const float*)d_in[4];

  char* ws = (char*)d_ws;
  uint4* qf  = (uint4*)ws;                          // 2,621,440 B
  uint4* kf  = (uint4*)(ws + 2621440);              // 2,621,440 B
  uint4* vf  = (uint4*)(ws + 2 * 2621440);          // 2,621,440 B
  float* acc = (float*)(ws + 3 * 2621440);          // 5,898,240 B (36 planes)

  qkv_kernel<<<dim3(160, 4), 256, 0, stream>>>(x, Wq, Wk, Wv, qf, kf, vf, acc);
  attn_kernel<<<1600, 256, 0, stream>>>(qf, kf, vf, acc);
  proj_kernel<<<640, 64, 0, stream>>>(acc, x, Wo, (float*)d_out);
}

// Round 9
// 132.274 us; speedup vs baseline: 1.6217x; 1.0453x over previous
//
#include <hip/hip_runtime.h>
#include <stdint.h>

#define NT 5
#define NC 32
#define NH 4
#define HW 4096             // 64*64
#define NPIX 40960          // (b*t)*HW
#define QS 0.51006972789f   // (1/sqrt(8)) * log2(e): fold scale + ln->log2 into q
#define EBIAS 12.0f         // softmax shift: p = 2^(e-EBIAS); cancels in acc/l

typedef _Float16 half_t;
typedef half_t h2 __attribute__((ext_vector_type(2)));

static __device__ __forceinline__ h2 as_h2(uint32_t u) {
  union { uint32_t u; h2 h; } c; c.u = u; return c.h;
}
static __device__ __forceinline__ uint32_t pack_h2(float a, float b) {
  union { h2 h; uint32_t u; } c;
  c.h.x = (half_t)a; c.h.y = (half_t)b;
  return c.u;
}

#if __has_builtin(__builtin_amdgcn_exp2f)
#define EXP2(x) __builtin_amdgcn_exp2f(x)
#else
#define EXP2(x) exp2f(x)
#endif

// dot8 with accumulator initialized at -EBIAS: e = q.k - 12, rides for free.
static __device__ __forceinline__ float dot8b(const uint4& a, const uint4& b) {
#if __has_builtin(__builtin_amdgcn_fdot2)
  float c = -EBIAS;
  c = __builtin_amdgcn_fdot2(as_h2(a.x), as_h2(b.x), c, false);
  c = __builtin_amdgcn_fdot2(as_h2(a.y), as_h2(b.y), c, false);
  c = __builtin_amdgcn_fdot2(as_h2(a.z), as_h2(b.z), c, false);
  c = __builtin_amdgcn_fdot2(as_h2(a.w), as_h2(b.w), c, false);
  return c;
#else
  const h2 a0 = as_h2(a.x), a1 = as_h2(a.y), a2 = as_h2(a.z), a3 = as_h2(a.w);
  const h2 b0 = as_h2(b.x), b1 = as_h2(b.y), b2 = as_h2(b.z), b3 = as_h2(b.w);
  float c = -EBIAS;
  c = fmaf((float)a0.x, (float)b0.x, c);
  c = fmaf((float)a0.y, (float)b0.y, c);
  c = fmaf((float)a1.x, (float)b1.x, c);
  c = fmaf((float)a1.y, (float)b1.y, c);
  c = fmaf((float)a2.x, (float)b2.x, c);
  c = fmaf((float)a2.y, (float)b2.y, c);
  c = fmaf((float)a3.x, (float)b3.x, c);
  c = fmaf((float)a3.y, (float)b3.y, c);
  return c;
#endif
}

// ---------------- Kernel A: QKV projection (head per blockIdx.y) ------------
// q,k,v -> fp16-packed uint4 [bt][h][pix]; q prescaled by QS.
// Also zeroes the 36-plane fp32 accumulator (re-zeroed every call).
__global__ __launch_bounds__(256) void qkv_kernel(
    const float* __restrict__ x,
    const float* __restrict__ Wq, const float* __restrict__ Wk,
    const float* __restrict__ Wv,
    uint4* __restrict__ qf, uint4* __restrict__ kf, uint4* __restrict__ vf,
    float* __restrict__ accbuf)
{
  const int p   = blockIdx.x * 256 + threadIdx.x;   // 0..40959
  const int h   = blockIdx.y;
  const int bt  = p >> 12;
  const int pix = p & 4095;

  // zero accumulator: 36*NPIX floats == 9 per (thread, blockIdx.y)
  const int gid = (blockIdx.y * 160 + blockIdx.x) * 256 + threadIdx.x; // 0..163839
  #pragma unroll
  for (int i = 0; i < 9; ++i) accbuf[(size_t)i * 163840 + gid] = 0.f;

  const float* xp = x + (size_t)bt * (NC * HW) + pix;
  float xc[NC];
  #pragma unroll
  for (int c = 0; c < NC; ++c) xc[c] = xp[(size_t)c * HW];

  float qv[8], kv8[8], vv8[8];
  #pragma unroll
  for (int j = 0; j < 8; ++j) {
    const int o = h * 8 + j;
    float aq = 0.f, ak = 0.f, av = 0.f;
    #pragma unroll
    for (int c = 0; c < NC; ++c) {
      const float xv = xc[c];
      aq = fmaf(xv, Wq[o * NC + c], aq);
      ak = fmaf(xv, Wk[o * NC + c], ak);
      av = fmaf(xv, Wv[o * NC + c], av);
    }
    qv[j] = aq * QS; kv8[j] = ak; vv8[j] = av;
  }
  const size_t base = ((size_t)bt * NH + h) * HW + pix;
  uint4 qq, kk, vv;
  qq.x = pack_h2(qv[0], qv[1]);  qq.y = pack_h2(qv[2], qv[3]);
  qq.z = pack_h2(qv[4], qv[5]);  qq.w = pack_h2(qv[6], qv[7]);
  kk.x = pack_h2(kv8[0], kv8[1]); kk.y = pack_h2(kv8[2], kv8[3]);
  kk.z = pack_h2(kv8[4], kv8[5]); kk.w = pack_h2(kv8[6], kv8[7]);
  vv.x = pack_h2(vv8[0], vv8[1]); vv.y = pack_h2(vv8[2], vv8[3]);
  vv.z = pack_h2(vv8[4], vv8[5]); vv.w = pack_h2(vv8[6], vv8[7]);
  qf[base] = qq;
  kf[base] = kk;
  vf[base] = vv;
}

// ---------------- Kernel B: neighborhood attention, LDS-staged --------------
// Block = 256 thr = 4 waves; lanes = 64 x-positions of a row; each wave owns a
// vertical query pair (y, y+D) sharing the key-row sweep. One frame per block.
// V-accumulators in packed fp16 (v_pk_fma_f16) with p biased by 2^-EBIAS so
// worst-case acc < 2^14 (fp16-safe); l in fp32. Bias cancels in proj's acc/l.
template <int R, int D>
static __device__ __forceinline__ void attn_body(
    int b, int t, int h, int s, int yb,
    const uint4* __restrict__ qf, const uint4* __restrict__ kf,
    const uint4* __restrict__ vf, float* __restrict__ accbuf,
    uint4* __restrict__ k_lds, uint4* __restrict__ v_lds)
{
  constexpr int LS    = 2 * R + 1;
  constexpr int NROWS = 8 + 2 * R;        // staged key rows (step D)
  const int tid  = threadIdx.x;
  const int w    = tid >> 6;              // wave 0..3
  const int lane = tid & 63;

  // first query row of this block (D2: yb&1 = row parity, 8 same-parity rows)
  const int y0 = (D == 1) ? (yb * 8) : ((yb & 1) + 2 * ((yb >> 1) * 8));

  // ---- stage NROWS full-width K,V rows into LDS (coalesced) ----
  const uint4* kg = kf + (size_t)((b * NT + s) * NH + h) * HW;
  const uint4* vg = vf + (size_t)((b * NT + s) * NH + h) * HW;
  for (int idx = tid; idx < NROWS * 64; idx += 256) {
    const int r  = idx >> 6, xs = idx & 63;
    int ys = y0 + (r - R) * D;
    ys = ys < 0 ? 0 : (ys > 63 ? 63 : ys);          // clamp; masked at compute
    const int pos = (D == 1) ? xs : ((xs & 1) * 32 + (xs >> 1));
    k_lds[r * 64 + pos] = kg[ys * 64 + xs];
    v_lds[r * 64 + pos] = vg[ys * 64 + xs];
  }
  __syncthreads();

  const int xp = lane >> 5;                          // D2 x-parity
  const int cb = (D == 1) ? lane : (lane & 31);      // compressed x
  const int x  = (D == 1) ? lane : (2 * (lane & 31) + xp);
  const int yA = y0 + 2 * w * D;
  const int yB = yA + D;
  const int pixA = yA * 64 + x, pixB = yB * 64 + x;

  const uint4* qp = qf + (size_t)((b * NT + t) * NH + h) * HW;
  const uint4 qA = qp[pixA];
  const uint4 qB = qp[pixB];

  float lA = 0.f, lB = 0.f;
  h2 aA[4], aB[4];
  const h2 z2 = { (half_t)0.f, (half_t)0.f };
  #pragma unroll
  for (int i = 0; i < 4; ++i) { aA[i] = z2; aB[i] = z2; }

  #pragma unroll 1
  for (int u = 0; u <= LS; ++u) {                    // key-row sweep, pair-shared
    const bool okA = (u < LS) && ((unsigned)(yA + (u - R) * D) < 64u);
    const bool okB = (u > 0)  && ((unsigned)(yB + (u - 1 - R) * D) < 64u);
    if (!(okA || okB)) continue;                     // wave-uniform skip
    const float mA = okA ? 1.f : 0.f, mB = okB ? 1.f : 0.f;
    const uint4* kr = k_lds + (2 * w + u) * 64;
    const uint4* vr = v_lds + (2 * w + u) * 64;
    #pragma unroll
    for (int dx = -R; dx <= R; ++dx) {
      const int  cx  = cb + dx;
      const bool okx = (unsigned)cx < (D == 1 ? 64u : 32u);
      const int  cc  = okx ? cx : 0;
      const int  pos = (D == 1) ? cc : (xp * 32 + cc);
      const uint4 kk = kr[pos];
      const uint4 vv = vr[pos];
      const h2 w0 = as_h2(vv.x), w1 = as_h2(vv.y), w2 = as_h2(vv.z), w3 = as_h2(vv.w);
      const float eA = dot8b(qA, kk);                // e - EBIAS, bias free
      const float eB = dot8b(qB, kk);
      const float pA = (okx ? mA : 0.f) * EXP2(eA);
      const float pB = (okx ? mB : 0.f) * EXP2(eB);
      lA += pA; lB += pB;
      const half_t pAh = (half_t)pA, pBh = (half_t)pB;
      const h2 pA2 = { pAh, pAh }, pB2 = { pBh, pBh };
      aA[0] += pA2 * w0; aA[1] += pA2 * w1; aA[2] += pA2 * w2; aA[3] += pA2 * w3;
      aB[0] += pB2 * w0; aB[1] += pB2 * w1; aB[2] += pB2 * w2; aB[3] += pB2 * w3;
    }
  }

  // ---- accumulate frame-partials: accbuf[h][comp(9)][btpix] ----
  const int btA = (b * NT + t) * HW + pixA;
  const int btB = (b * NT + t) * HW + pixB;
  float* ab = accbuf + (size_t)(h * 9) * NPIX;
  #pragma unroll
  for (int i = 0; i < 4; ++i) {
    atomicAdd(&ab[(size_t)(2 * i)     * NPIX + btA], (float)aA[i].x);
    atomicAdd(&ab[(size_t)(2 * i + 1) * NPIX + btA], (float)aA[i].y);
    atomicAdd(&ab[(size_t)(2 * i)     * NPIX + btB], (float)aB[i].x);
    atomicAdd(&ab[(size_t)(2 * i + 1) * NPIX + btB], (float)aB[i].y);
  }
  atomicAdd(&ab[(size_t)8 * NPIX + btA], lA);
  atomicAdd(&ab[(size_t)8 * NPIX + btB], lB);
}

__global__ __launch_bounds__(256) void attn_kernel(
    const uint4* __restrict__ qf, const uint4* __restrict__ kf,
    const uint4* __restrict__ vf, float* __restrict__ accbuf)
{
  __shared__ uint4 k_lds[16 * 64];   // 16 KB
  __shared__ uint4 v_lds[16 * 64];   // 16 KB
  const int bid = blockIdx.x;        // 1600 = 10(bt) * 5(s) * 8(yb) * 4(h)
  const int h   = bid & 3;           // head in low bits -> R3/R4 mix per CU
  int r = bid >> 2;
  const int yb = r & 7; r >>= 3;
  const int s  = r % 5;
  const int bt = r / 5;
  const int t = bt % NT, b = bt / NT;
  if      (h == 0) attn_body<3, 1>(b, t, 0, s, yb, qf, kf, vf, accbuf, k_lds, v_lds);
  else if (h == 1) attn_body<3, 2>(b, t, 1, s, yb, qf, kf, vf, accbuf, k_lds, v_lds);
  else if (h == 2) attn_body<4, 1>(b, t, 2, s, yb, qf, kf, vf, accbuf, k_lds, v_lds);
  else             attn_body<4, 2>(b, t, 3, s, yb, qf, kf, vf, accbuf, k_lds, v_lds);
}

// ---------------- Kernel C: normalize + output projection + residual --------
__global__ __launch_bounds__(64) void proj_kernel(
    const float* __restrict__ accbuf, const float* __restrict__ x,
    const float* __restrict__ Wo, float* __restrict__ out)
{
  const int p   = blockIdx.x * 64 + threadIdx.x;   // btpix 0..40959
  const int bt  = p >> 12;
  const int pix = p & 4095;

  float oc[32];
  #pragma unroll
  for (int h = 0; h < NH; ++h) {
    const float* ab = accbuf + (size_t)(h * 9) * NPIX + p;
    float a[8];
    #pragma unroll
    for (int i = 0; i < 8; ++i) a[i] = ab[(size_t)i * NPIX];
    const float inv = 1.0f / ab[(size_t)8 * NPIX];
    #pragma unroll
    for (int i = 0; i < 8; ++i) oc[h * 8 + i] = a[i] * inv;
  }

  const float* xp = x + (size_t)bt * (NC * HW) + pix;
  float* yp = out + (size_t)bt * (NC * HW) + pix;
  #pragma unroll
  for (int o = 0; o < NC; ++o) {
    float acc = xp[(size_t)o * HW];                 // residual
    #pragma unroll
    for (int c = 0; c < NC; ++c)
      acc = fmaf(oc[c], Wo[o * NC + c], acc);
    yp[(size_t)o * HW] = acc;
  }
}

extern "C" void kernel_launch(void* const* d_in, const int* in_sizes, int n_in,
                              void* d_out, int out_size, void* d_ws, size_t ws_size,
                              hipStream_t stream)
{
  const float* x  = (const float*)d_in[0];
  const float* Wq = (const float*)d_in[1];
  const float* Wk = (const float*)d_in[2];
  const float* Wv = (const float*)d_in[3];
  const float* Wo = (const float*)d_in[4];

  char* ws = (char*)d_ws;
  uint4* qf  = (uint4*)ws;                          // 2,621,440 B
  uint4* kf  = (uint4*)(ws + 2621440);              // 2,621,440 B
  uint4* vf  = (uint4*)(ws + 2 * 2621440);          // 2,621,440 B
  float* acc = (float*)(ws + 3 * 2621440);          // 5,898,240 B (36 planes)

  qkv_kernel<<<dim3(160, 4), 256, 0, stream>>>(x, Wq, Wk, Wv, qf, kf, vf, acc);
  attn_kernel<<<1600, 256, 0, stream>>>(qf, kf, vf, acc);
  proj_kernel<<<640, 64, 0, stream>>>(acc, x, Wo, (float*)d_out);
}